// Round 1
// baseline (713.117 us; speedup 1.0000x reference)
//
#include <hip/hip_runtime.h>
#include <hip/hip_bf16.h>

// Problem constants
#define B_    4096
#define ARITY 6
#define EMB   100
#define NF    200
#define FC    1200
#define NROWS (B_*ARITY)   // 24576 (b,a) rows
#define BN_EPS 1e-5f

// ws layout (float offsets). Total 14,746,400 floats = 59 MB.
#define M_OFF     0
#define MINA_OFF  (NROWS*NF)            // 4,915,200
#define MINC_OFF  (MINA_OFF + B_*FC)    // 9,830,400
#define SUM_OFF   (MINC_OFF + B_*FC)    // 14,745,600
#define SUMSQ_OFF (SUM_OFF + NF)
#define SCALE_OFF (SUMSQ_OFF + NF)
#define SHIFT_OFF (SCALE_OFF + NF)

// ---------------- Kernel 1: gather + conv GEMM + BN partial stats ----------
// Block: 256 threads, 64 rows x 200 features, K=200 in chunks of 40.
__launch_bounds__(256)
__global__ void k1_conv(const int* __restrict__ x,
                        const float* __restrict__ er,
                        const float* __restrict__ ev,
                        const float* __restrict__ cw,
                        const float* __restrict__ cb,
                        float* __restrict__ m,
                        float* __restrict__ gsum,
                        float* __restrict__ gsumsq)
{
    __shared__ float s_cat[64][44];
    __shared__ float s_w[224][44];   // f>=200 zero-filled; also reused for stats reduce
    __shared__ int   s_ri[64], s_vi[64];

    const int t  = threadIdx.x;
    const int R0 = blockIdx.x * 64;

    if (t < 64) {
        int R = R0 + t;
        int b = R / ARITY, a = R - b * ARITY;
        // int64-vs-int32 detection: if x is int64, the high words are 0.
        bool is64 = ((x[1] | x[3] | x[5] | x[7]) == 0);
        int base = b * (2*ARITY) + 2*a;
        if (is64) { s_ri[t] = x[2*base]; s_vi[t] = x[2*(base+1)]; }
        else      { s_ri[t] = x[base];   s_vi[t] = x[base+1];     }
    }
    __syncthreads();

    float acc[8][7];
    #pragma unroll
    for (int a2 = 0; a2 < 8; ++a2)
        #pragma unroll
        for (int j = 0; j < 7; ++j) acc[a2][j] = 0.0f;

    const int row_q = t & 3;   // 4 threads per row for cat load
    const int row_r = t >> 2;  // 0..63
    const float* rrow = er + (size_t)s_ri[row_r] * EMB;
    const float* vrow = ev + (size_t)s_vi[row_r] * EMB;
    const int ry = t >> 5;     // 0..7
    const int cx = t & 31;     // 0..31

    for (int k0 = 0; k0 < NF; k0 += 40) {
        // cat chunk: 64 rows x 40 elems
        #pragma unroll
        for (int u = 0; u < 10; ++u) {
            int kk = row_q * 10 + u;
            int e  = k0 + kk;
            s_cat[row_r][kk] = (e < EMB) ? rrow[e] : vrow[e - EMB];
        }
        // w chunk: 224 x 40 (f>=200 -> 0)
        #pragma unroll
        for (int s = 0; s < 35; ++s) {
            int idx = t + 256*s;      // < 8960 = 224*40
            int f = idx / 40, kk = idx - f*40;
            s_w[f][kk] = (f < NF) ? cw[f*NF + (k0+kk)] : 0.0f;
        }
        __syncthreads();
        #pragma unroll
        for (int kb = 0; kb < 40; kb += 4) {
            float4 wv[7];
            #pragma unroll
            for (int j = 0; j < 7; ++j)
                wv[j] = *(const float4*)&s_w[cx + 32*j][kb];
            #pragma unroll
            for (int a2 = 0; a2 < 8; ++a2) {
                float4 cv = *(const float4*)&s_cat[ry*8 + a2][kb];
                #pragma unroll
                for (int j = 0; j < 7; ++j) {
                    acc[a2][j] += cv.x * wv[j].x;
                    acc[a2][j] += cv.y * wv[j].y;
                    acc[a2][j] += cv.z * wv[j].z;
                    acc[a2][j] += cv.w * wv[j].w;
                }
            }
        }
        __syncthreads();
    }

    // epilogue: +bias, write m, per-thread stats
    float ps[7], pq[7];
    #pragma unroll
    for (int j = 0; j < 7; ++j) { ps[j] = 0.0f; pq[j] = 0.0f; }
    #pragma unroll
    for (int a2 = 0; a2 < 8; ++a2) {
        int R = R0 + ry*8 + a2;
        #pragma unroll
        for (int j = 0; j < 7; ++j) {
            int f = cx + 32*j;
            if (f < NF) {
                float v = acc[a2][j] + cb[f];
                m[(size_t)R*NF + f] = v;
                ps[j] += v; pq[j] += v*v;
            }
        }
    }
    // block reduce stats via reused s_w area: [2][8][224]
    float* s_red = &s_w[0][0];
    #pragma unroll
    for (int j = 0; j < 7; ++j) {
        int col = cx + 32*j;
        s_red[ry*224 + col]        = ps[j];
        s_red[1792 + ry*224 + col] = pq[j];
    }
    __syncthreads();
    if (t < NF) {
        float s = 0.0f, q = 0.0f;
        #pragma unroll
        for (int r = 0; r < 8; ++r) { s += s_red[r*224 + t]; q += s_red[1792 + r*224 + t]; }
        atomicAdd(&gsum[t], s);
        atomicAdd(&gsumsq[t], q);
    }
}

// ---------------- Kernel 2: finalize BN scale/shift ------------------------
__global__ void k2_stats(const float* __restrict__ gsum,
                         const float* __restrict__ gsumsq,
                         const float* __restrict__ gamma,
                         const float* __restrict__ beta,
                         float* __restrict__ scale,
                         float* __restrict__ shift)
{
    int t = threadIdx.x;
    if (t < NF) {
        float inv = 1.0f / (float)NROWS;
        float mu  = gsum[t] * inv;
        float var = gsumsq[t] * inv - mu*mu;
        float rs  = rsqrtf(var + BN_EPS);
        float sc  = rs * gamma[t];
        scale[t] = sc;
        shift[t] = beta[t] - mu*sc;
    }
}

// ---------------- Kernel 3: big GEMM (N=2400) + min over arity -------------
// Block 256: tile 48 rows (8 b-groups x 6) x 96 cols, K=200 in chunks of 40.
__launch_bounds__(256)
__global__ void k3_pair(const float* __restrict__ m,
                        const float* __restrict__ scale,
                        const float* __restrict__ shift,
                        const float* __restrict__ gW,
                        float* __restrict__ minA,
                        float* __restrict__ minC)
{
    __shared__ float s_m[48][44];
    __shared__ float s_w[96][44];
    const int t  = threadIdx.x;
    const int nb = blockIdx.x;   // 0..24
    const int mb = blockIdx.y;   // 0..511
    const int R0 = mb * 48;
    const int N0 = nb * 96;

    float acc[6][3];
    #pragma unroll
    for (int i = 0; i < 6; ++i)
        #pragma unroll
        for (int j = 0; j < 3; ++j) acc[i][j] = 0.0f;

    const int ry = t >> 5;  // 0..7 : b-group
    const int cx = t & 31;

    for (int k0 = 0; k0 < NF; k0 += 40) {
        // m tile 48x40 with BN+relu applied on load
        #pragma unroll
        for (int s = 0; s < 8; ++s) {
            int idx = t + 256*s;    // < 2048, valid < 1920
            if (idx < 1920) {
                int row = idx / 40, kk = idx - row*40;
                int gk = k0 + kk;
                float raw = m[(size_t)(R0+row)*NF + gk];
                s_m[row][kk] = fmaxf(raw * scale[gk] + shift[gk], 0.0f);
            }
        }
        // W' tile 96x40 : n<1200 -> gW[n][gk], else gW[n-1200][200+gk]
        #pragma unroll
        for (int s = 0; s < 15; ++s) {
            int idx = t + 256*s;    // < 3840 exactly
            int nl = idx / 40, kk = idx - nl*40;
            int n  = N0 + nl;
            int gk = k0 + kk;
            s_w[nl][kk] = (n < FC) ? gW[(size_t)n*400 + gk]
                                   : gW[(size_t)(n-FC)*400 + 200 + gk];
        }
        __syncthreads();
        #pragma unroll
        for (int kb = 0; kb < 40; kb += 4) {
            float4 wv[3];
            #pragma unroll
            for (int j = 0; j < 3; ++j)
                wv[j] = *(const float4*)&s_w[cx + 32*j][kb];
            #pragma unroll
            for (int i = 0; i < 6; ++i) {
                float4 mv = *(const float4*)&s_m[ry*6 + i][kb];
                #pragma unroll
                for (int j = 0; j < 3; ++j) {
                    acc[i][j] += mv.x * wv[j].x;
                    acc[i][j] += mv.y * wv[j].y;
                    acc[i][j] += mv.z * wv[j].z;
                    acc[i][j] += mv.w * wv[j].w;
                }
            }
        }
        __syncthreads();
    }

    // min over the 6 arity rows, write minA/minC
    int b = mb*8 + ry;
    #pragma unroll
    for (int j = 0; j < 3; ++j) {
        float v = acc[0][j];
        #pragma unroll
        for (int i = 1; i < 6; ++i) v = fminf(v, acc[i][j]);
        int n = N0 + cx + 32*j;
        if (n < FC) minA[(size_t)b*FC + n]        = v;
        else        minC[(size_t)b*FC + (n - FC)] = v;
    }
}

// ---------------- Kernel 4: relu(minA+minC+gb) . fW + fb -------------------
__launch_bounds__(256)
__global__ void k4_final(const float* __restrict__ minA,
                         const float* __restrict__ minC,
                         const float* __restrict__ gb,
                         const float* __restrict__ fW,
                         const float* __restrict__ fb,
                         float* __restrict__ out)
{
    const int b = blockIdx.x;
    const int t = threadIdx.x;
    float p = 0.0f;
    for (int o = t; o < FC; o += 256) {
        float v = minA[(size_t)b*FC + o] + minC[(size_t)b*FC + o] + gb[o];
        p += fmaxf(v, 0.0f) * fW[o];
    }
    #pragma unroll
    for (int off = 32; off > 0; off >>= 1) p += __shfl_down(p, off);
    __shared__ float s[4];
    if ((t & 63) == 0) s[t >> 6] = p;
    __syncthreads();
    if (t == 0) out[b] = s[0] + s[1] + s[2] + s[3] + fb[0];
}

extern "C" void kernel_launch(void* const* d_in, const int* in_sizes, int n_in,
                              void* d_out, int out_size, void* d_ws, size_t ws_size,
                              hipStream_t stream)
{
    const int*   x   = (const int*)  d_in[0];
    const float* er  = (const float*)d_in[1];
    const float* ev  = (const float*)d_in[2];
    const float* cw  = (const float*)d_in[3];
    const float* cb  = (const float*)d_in[4];
    const float* gam = (const float*)d_in[5];
    const float* bet = (const float*)d_in[6];
    const float* gW  = (const float*)d_in[7];
    const float* gb  = (const float*)d_in[8];
    const float* fW  = (const float*)d_in[9];
    const float* fb  = (const float*)d_in[10];

    float* ws     = (float*)d_ws;
    float* m      = ws + M_OFF;
    float* minA   = ws + MINA_OFF;
    float* minC   = ws + MINC_OFF;
    float* gsum   = ws + SUM_OFF;
    float* gsumsq = ws + SUMSQ_OFF;
    float* scale  = ws + SCALE_OFF;
    float* shift  = ws + SHIFT_OFF;

    // zero the stats accumulators (graph-capturable memset node)
    hipMemsetAsync(gsum, 0, 2*NF*sizeof(float), stream);

    k1_conv <<<NROWS/64, 256, 0, stream>>>(x, er, ev, cw, cb, m, gsum, gsumsq);
    k2_stats<<<1, 256, 0, stream>>>(gsum, gsumsq, gam, bet, scale, shift);
    k3_pair <<<dim3(25, NROWS/48), 256, 0, stream>>>(m, scale, shift, gW, minA, minC);
    k4_final<<<B_, 256, 0, stream>>>(minA, minC, gb, fW, fb, (float*)d_out);
}

// Round 2
// 193.751 us; speedup vs baseline: 3.6806x; 3.6806x over previous
//
#include <hip/hip_runtime.h>
#include <hip/hip_bf16.h>
#include <hip/hip_fp16.h>

// Problem constants
#define B_    4096
#define ARITY 6
#define EMB   100
#define NF    200
#define FC    1200
#define NROWS (B_*ARITY)   // 24576
#define BN_EPS 1e-5f
#define KP    224          // K (=2*NF=400 split into two 200 halves) padded to 224

typedef _Float16 half8 __attribute__((ext_vector_type(8)));
typedef float f32x4 __attribute__((ext_vector_type(4)));

// ws layout (float offsets):
//  [0 .. 2752512)          m_h   (24576*224 f16)
//  [2752512 .. 3021312)    W_h   (2400*224 f16)
//  [3021312 .. 3022112)    stats (gsum,gsumsq,scale,shift  4*200)
//  [3022112 .. 7937312)    minA  (4096*1200 f32)   -- also aliases fp32 m (dead by k3)
//  [7937312 .. 12852512)   minC  (4096*1200 f32)
#define MH_OFF    0
#define WH_OFF    2752512
#define STAT_OFF  3021312
#define MINA_OFF  3022112
#define MINC_OFF  7937312
#define M_OFF     MINA_OFF   // fp32 m aliases minA/minC region (dead before k3 writes)

__device__ __forceinline__ void gload16(const void* g, void* l) {
    __builtin_amdgcn_global_load_lds(
        (const __attribute__((address_space(1))) void*)g,
        (__attribute__((address_space(3))) void*)l, 16, 0, 0);
}

// ---------------- Kernel 1: gather + conv GEMM + BN partial stats ----------
__launch_bounds__(256)
__global__ void k1_conv(const int* __restrict__ x,
                        const float* __restrict__ er,
                        const float* __restrict__ ev,
                        const float* __restrict__ cw,
                        const float* __restrict__ cb,
                        float* __restrict__ m,
                        float* __restrict__ gsum,
                        float* __restrict__ gsumsq)
{
    __shared__ float s_cat[64][44];
    __shared__ float s_w[224][44];
    __shared__ int   s_ri[64], s_vi[64];

    const int t  = threadIdx.x;
    const int R0 = blockIdx.x * 64;

    if (t < 64) {
        int R = R0 + t;
        int b = R / ARITY, a = R - b * ARITY;
        bool is64 = ((x[1] | x[3] | x[5] | x[7]) == 0);
        int base = b * (2*ARITY) + 2*a;
        if (is64) { s_ri[t] = x[2*base]; s_vi[t] = x[2*(base+1)]; }
        else      { s_ri[t] = x[base];   s_vi[t] = x[base+1];     }
    }
    __syncthreads();

    float acc[8][7];
    #pragma unroll
    for (int a2 = 0; a2 < 8; ++a2)
        #pragma unroll
        for (int j = 0; j < 7; ++j) acc[a2][j] = 0.0f;

    const int row_q = t & 3;
    const int row_r = t >> 2;
    const float* rrow = er + (size_t)s_ri[row_r] * EMB;
    const float* vrow = ev + (size_t)s_vi[row_r] * EMB;
    const int ry = t >> 5;
    const int cx = t & 31;

    for (int k0 = 0; k0 < NF; k0 += 40) {
        #pragma unroll
        for (int u = 0; u < 10; ++u) {
            int kk = row_q * 10 + u;
            int e  = k0 + kk;
            s_cat[row_r][kk] = (e < EMB) ? rrow[e] : vrow[e - EMB];
        }
        #pragma unroll
        for (int s = 0; s < 35; ++s) {
            int idx = t + 256*s;
            int f = idx / 40, kk = idx - f*40;
            s_w[f][kk] = (f < NF) ? cw[f*NF + (k0+kk)] : 0.0f;
        }
        __syncthreads();
        #pragma unroll
        for (int kb = 0; kb < 40; kb += 4) {
            float4 wv[7];
            #pragma unroll
            for (int j = 0; j < 7; ++j)
                wv[j] = *(const float4*)&s_w[cx + 32*j][kb];
            #pragma unroll
            for (int a2 = 0; a2 < 8; ++a2) {
                float4 cv = *(const float4*)&s_cat[ry*8 + a2][kb];
                #pragma unroll
                for (int j = 0; j < 7; ++j) {
                    acc[a2][j] += cv.x * wv[j].x;
                    acc[a2][j] += cv.y * wv[j].y;
                    acc[a2][j] += cv.z * wv[j].z;
                    acc[a2][j] += cv.w * wv[j].w;
                }
            }
        }
        __syncthreads();
    }

    float ps[7], pq[7];
    #pragma unroll
    for (int j = 0; j < 7; ++j) { ps[j] = 0.0f; pq[j] = 0.0f; }
    #pragma unroll
    for (int a2 = 0; a2 < 8; ++a2) {
        int R = R0 + ry*8 + a2;
        #pragma unroll
        for (int j = 0; j < 7; ++j) {
            int f = cx + 32*j;
            if (f < NF) {
                float v = acc[a2][j] + cb[f];
                m[(size_t)R*NF + f] = v;
                ps[j] += v; pq[j] += v*v;
            }
        }
    }
    float* s_red = &s_w[0][0];
    #pragma unroll
    for (int j = 0; j < 7; ++j) {
        int col = cx + 32*j;
        s_red[ry*224 + col]        = ps[j];
        s_red[1792 + ry*224 + col] = pq[j];
    }
    __syncthreads();
    if (t < NF) {
        float s = 0.0f, q = 0.0f;
        #pragma unroll
        for (int r = 0; r < 8; ++r) { s += s_red[r*224 + t]; q += s_red[1792 + r*224 + t]; }
        atomicAdd(&gsum[t], s);
        atomicAdd(&gsumsq[t], q);
    }
}

// ---------------- Kernel 2: finalize BN scale/shift ------------------------
__global__ void k2_stats(const float* __restrict__ gsum,
                         const float* __restrict__ gsumsq,
                         const float* __restrict__ gamma,
                         const float* __restrict__ beta,
                         float* __restrict__ scale,
                         float* __restrict__ shift)
{
    int t = threadIdx.x;
    if (t < NF) {
        float inv = 1.0f / (float)NROWS;
        float mu  = gsum[t] * inv;
        float var = gsumsq[t] * inv - mu*mu;
        float rs  = rsqrtf(var + BN_EPS);
        float sc  = rs * gamma[t];
        scale[t] = sc;
        shift[t] = beta[t] - mu*sc;
    }
}

// ---------------- Kernel 2h: convert to f16 (BN+relu folded; K padded) -----
// m_h[R][224] = relu(m*scale+shift) f16 ;  W_h[n][224] = gW' f16
#define MH8 (NROWS*28)   // 688128 half8-chunks for m_h
#define WH8 (2400*28)    // 67200 chunks for W_h
__launch_bounds__(256)
__global__ void k_h(const float* __restrict__ m,
                    const float* __restrict__ scale,
                    const float* __restrict__ shift,
                    const float* __restrict__ gW,
                    _Float16* __restrict__ m_h,
                    _Float16* __restrict__ W_h)
{
    int id = blockIdx.x * 256 + threadIdx.x;
    if (id < MH8) {
        int R = id / 28, c8 = (id - R*28) * 8;
        half8 o;
        #pragma unroll
        for (int j = 0; j < 8; ++j) {
            int k = c8 + j;
            float v = 0.f;
            if (k < NF) v = fmaxf(m[(size_t)R*NF + k] * scale[k] + shift[k], 0.f);
            o[j] = (_Float16)v;
        }
        *(half8*)&m_h[(size_t)R*KP + c8] = o;
    } else if (id < MH8 + WH8) {
        int id2 = id - MH8;
        int n = id2 / 28, c8 = (id2 - n*28) * 8;
        half8 o;
        #pragma unroll
        for (int j = 0; j < 8; ++j) {
            int k = c8 + j;
            float v = 0.f;
            if (k < NF) v = (n < FC) ? gW[(size_t)n*400 + k]
                                     : gW[(size_t)(n-FC)*400 + 200 + k];
            o[j] = (_Float16)v;
        }
        *(half8*)&W_h[(size_t)n*KP + c8] = o;
    }
}

// ---------------- Kernel 3: f16 MFMA GEMM + min over arity -----------------
// Block 256 (4 waves as 2M x 2N), tile 96M x 160N, wave tile 48x80.
// K = 224 in 7 steps of 32, single-buffer LDS staged via global_load_lds.
__launch_bounds__(256)
__global__ void k3_mfma(const _Float16* __restrict__ m_h,
                        const _Float16* __restrict__ W_h,
                        float* __restrict__ minA,
                        float* __restrict__ minC)
{
    __shared__ __align__(16) char smem[16384];
    _Float16* s_a = (_Float16*)smem;            // 96 x 32 f16 (6 KB)
    _Float16* s_b = (_Float16*)(smem + 6144);   // 160 x 32 f16 (10 KB)
    float*    s_ep = (float*)smem;              // epilogue scratch (reuse)

    const int t    = threadIdx.x;
    const int lane = t & 63;
    const int wave = t >> 6;
    const int wm   = wave >> 1, wn = wave & 1;
    const int R0   = blockIdx.y * 96;
    const int N0   = blockIdx.x * 160;
    const int q    = lane >> 4, cx = lane & 15;

    f32x4 acc[3][5];
    #pragma unroll
    for (int mf = 0; mf < 3; ++mf)
        #pragma unroll
        for (int nf = 0; nf < 5; ++nf)
            acc[mf][nf] = (f32x4){0.f,0.f,0.f,0.f};

    for (int ks = 0; ks < 7; ++ks) {
        const int k0 = ks * 32;
        // stage: A tile 96x32 (6 wave-chunks of 1KB), B tile 160x32 (10 chunks)
        #pragma unroll
        for (int i = 0; i < 4; ++i) {
            int j = wave + 4*i;          // 0..15, wave-uniform
            if (j < 6) {
                int c = j*64 + lane;     // 16B chunk id within A tile
                int row = c >> 2, slot = c & 3;
                gload16(m_h + (size_t)(R0+row)*KP + k0 + slot*8,
                        (char*)s_a + j*1024);
            } else {
                int c = (j-6)*64 + lane;
                int row = c >> 2, slot = c & 3;
                gload16(W_h + (size_t)(N0+row)*KP + k0 + slot*8,
                        (char*)s_b + (j-6)*1024);
            }
        }
        __syncthreads();

        half8 av[3], bv[5];
        #pragma unroll
        for (int mf = 0; mf < 3; ++mf)
            av[mf] = *(const half8*)&s_a[(wm*48 + mf*16 + cx)*32 + q*8];
        #pragma unroll
        for (int nf = 0; nf < 5; ++nf)
            bv[nf] = *(const half8*)&s_b[(wn*80 + nf*16 + cx)*32 + q*8];
        #pragma unroll
        for (int mf = 0; mf < 3; ++mf)
            #pragma unroll
            for (int nf = 0; nf < 5; ++nf)
                acc[mf][nf] = __builtin_amdgcn_mfma_f32_16x16x32_f16(
                                  av[mf], bv[nf], acc[mf][nf], 0, 0, 0);
        __syncthreads();
    }

    // Epilogue: min over 6 consecutive M-rows. 4 passes of 12 rows per wave,
    // each wave uses a private 12x80 f32 region (reuses stage LDS).
    float* wep = s_ep + wave * 960;
    #pragma unroll
    for (int p = 0; p < 4; ++p) {
        __syncthreads();
        #pragma unroll
        for (int mf = 0; mf < 3; ++mf)
            #pragma unroll
            for (int reg = 0; reg < 4; ++reg) {
                int r = mf*16 + q*4 + reg;     // wave-local row 0..47
                if (r >= p*12 && r < p*12 + 12) {
                    #pragma unroll
                    for (int nf = 0; nf < 5; ++nf)
                        wep[(r - p*12)*80 + nf*16 + cx] = acc[mf][nf][reg];
                }
            }
        __syncthreads();
        for (int idx = lane; idx < 160; idx += 64) {
            int g = idx / 80, c = idx - g*80;
            float v = wep[(6*g)*80 + c];
            #pragma unroll
            for (int r2 = 1; r2 < 6; ++r2) v = fminf(v, wep[(6*g + r2)*80 + c]);
            int bb = (R0/6) + wm*8 + p*2 + g;       // batch index
            int n  = N0 + wn*80 + c;
            if (n < FC) minA[(size_t)bb*FC + n]        = v;
            else        minC[(size_t)bb*FC + (n - FC)] = v;
        }
    }
}

// ---------------- Kernel 4: relu(minA+minC+gb) . fW + fb -------------------
__launch_bounds__(256)
__global__ void k4_final(const float* __restrict__ minA,
                         const float* __restrict__ minC,
                         const float* __restrict__ gb,
                         const float* __restrict__ fW,
                         const float* __restrict__ fb,
                         float* __restrict__ out)
{
    const int b = blockIdx.x;
    const int t = threadIdx.x;
    float p = 0.0f;
    for (int o = t; o < FC; o += 256) {
        float v = minA[(size_t)b*FC + o] + minC[(size_t)b*FC + o] + gb[o];
        p += fmaxf(v, 0.0f) * fW[o];
    }
    #pragma unroll
    for (int off = 32; off > 0; off >>= 1) p += __shfl_down(p, off);
    __shared__ float s[4];
    if ((t & 63) == 0) s[t >> 6] = p;
    __syncthreads();
    if (t == 0) out[b] = s[0] + s[1] + s[2] + s[3] + fb[0];
}

extern "C" void kernel_launch(void* const* d_in, const int* in_sizes, int n_in,
                              void* d_out, int out_size, void* d_ws, size_t ws_size,
                              hipStream_t stream)
{
    const int*   x   = (const int*)  d_in[0];
    const float* er  = (const float*)d_in[1];
    const float* ev  = (const float*)d_in[2];
    const float* cw  = (const float*)d_in[3];
    const float* cb  = (const float*)d_in[4];
    const float* gam = (const float*)d_in[5];
    const float* bet = (const float*)d_in[6];
    const float* gW  = (const float*)d_in[7];
    const float* gb  = (const float*)d_in[8];
    const float* fW  = (const float*)d_in[9];
    const float* fb  = (const float*)d_in[10];

    float* ws = (float*)d_ws;
    _Float16* m_h  = (_Float16*)(ws + MH_OFF);
    _Float16* W_h  = (_Float16*)(ws + WH_OFF);
    float* gsum    = ws + STAT_OFF;
    float* gsumsq  = gsum + NF;
    float* scale   = gsum + 2*NF;
    float* shift   = gsum + 3*NF;
    float* minA    = ws + MINA_OFF;
    float* minC    = ws + MINC_OFF;
    float* m       = ws + M_OFF;    // fp32 m aliases minA/minC (dead before k3)

    hipMemsetAsync(gsum, 0, 2*NF*sizeof(float), stream);

    k1_conv <<<NROWS/64, 256, 0, stream>>>(x, er, ev, cw, cb, m, gsum, gsumsq);
    k2_stats<<<1, 256, 0, stream>>>(gsum, gsumsq, gam, bet, scale, shift);
    k_h     <<<(MH8 + WH8 + 255)/256, 256, 0, stream>>>(m, scale, shift, gW, m_h, W_h);
    k3_mfma <<<dim3(15, 256), 256, 0, stream>>>(m_h, W_h, minA, minC);
    k4_final<<<B_, 256, 0, stream>>>(minA, minC, gb, fW, fb, (float*)d_out);
}

// Round 3
// 135.224 us; speedup vs baseline: 5.2736x; 1.4328x over previous
//
#include <hip/hip_runtime.h>
#include <hip/hip_bf16.h>
#include <hip/hip_fp16.h>

#define B_    4096
#define ARITY 6
#define EMB   100
#define NF    200
#define FC    1200
#define NROWS (B_*ARITY)   // 24576
#define BN_EPS 1e-5f
#define KP    224

typedef _Float16 half8 __attribute__((ext_vector_type(8)));
typedef _Float16 half4 __attribute__((ext_vector_type(4)));
typedef float f32x4 __attribute__((ext_vector_type(4)));

// ws layout (float offsets):
#define MRAW_OFF  0              // m_raw f16 [24576][200]  -> 2,457,600 f
#define MH_OFF    2457600        // m_h   f16 [24576][224]  -> 2,752,512 f
#define WH_OFF    5210112        // W_h   f16 [2400][224]   ->   268,800 f
#define WHI_OFF   5478912        // Whi   f16 [224][224]    ->    25,088 f
#define WLO_OFF   5504000        // Wlo   f16 [224][224]    ->    25,088 f
#define STAT_OFF  5529088        // gshad[16][400] + scale[200] + shift[200]

__device__ __forceinline__ void gload16(const void* g, void* l) {
    __builtin_amdgcn_global_load_lds(
        (const __attribute__((address_space(1))) void*)g,
        (__attribute__((address_space(3))) void*)l, 16, 0, 0);
}

// ---------------- k0: weight prep (split-f16 conv W, paired+swizzled W_h) --
// Swizzle: within each [row][32] f16 K-tile, 16B-slot s -> s ^ ((row>>1)&3).
__launch_bounds__(256)
__global__ void k0_prep(const float* __restrict__ cw, const float* __restrict__ gW,
                        _Float16* __restrict__ whi, _Float16* __restrict__ wlo,
                        _Float16* __restrict__ W_h)
{
    int id = blockIdx.x * 256 + threadIdx.x;
    if (id < 224*28) {
        int f = id / 28, s = id - f*28;
        int tile = s >> 2, ls = s & 3, key = (f >> 1) & 3;
        int col = tile*32 + (ls ^ key)*8;
        half8 h, l;
        #pragma unroll
        for (int j = 0; j < 8; ++j) {
            int k = s*8 + j;
            float v = (f < NF && k < NF) ? cw[f*NF + k] : 0.f;
            _Float16 hi = (_Float16)v;
            h[j] = hi; l[j] = (_Float16)(v - (float)hi);
        }
        *(half8*)&whi[f*KP + col] = h;
        *(half8*)&wlo[f*KP + col] = l;
    } else if (id < 224*28 + 2400*28) {
        int id2 = id - 224*28;
        int n = id2 / 28, s = id2 - n*28;
        int o = n >> 1, hf = n & 1;
        int tile = s >> 2, ls = s & 3, key = (n >> 1) & 3;
        int col = tile*32 + (ls ^ key)*8;
        half8 h;
        #pragma unroll
        for (int j = 0; j < 8; ++j) {
            int k = s*8 + j;
            float v = (k < NF) ? gW[(size_t)o*400 + hf*200 + k] : 0.f;
            h[j] = (_Float16)v;
        }
        *(half8*)&W_h[(size_t)n*KP + col] = h;
    }
}

// ---------------- k1: gather + split-f16 MFMA conv + stats -----------------
// Block 256 (4 waves 2Mx2N), tile 32M x 224N, K=224 in 7 steps of 32.
__launch_bounds__(256)
__global__ void k1_mfma(const int* __restrict__ x,
                        const float* __restrict__ er,
                        const float* __restrict__ ev,
                        const _Float16* __restrict__ whi,
                        const _Float16* __restrict__ wlo,
                        const float* __restrict__ cb,
                        _Float16* __restrict__ m_raw,
                        float* __restrict__ gshad)
{
    __shared__ __align__(16) _Float16 s_ah[32*32], s_al[32*32];
    __shared__ __align__(16) _Float16 s_wh[224*32], s_wl[224*32];
    __shared__ float s_sum[200], s_sq[200];
    __shared__ int s_ri[32], s_vi[32];

    const int t = threadIdx.x, lane = t & 63, wave = t >> 6;
    const int wm = wave >> 1, wn = wave & 1;
    const int R0 = blockIdx.x * 32;
    const int q = lane >> 4, cx = lane & 15;
    const int rdsw = (q ^ ((cx >> 1) & 3)) * 8;

    if (t < 32) {
        int R = R0 + t, b = R / ARITY, a = R - b * ARITY;
        bool is64 = ((x[1] | x[3] | x[5] | x[7]) == 0);
        int base = b * (2*ARITY) + 2*a;
        s_ri[t] = is64 ? x[2*base]     : x[base];
        s_vi[t] = is64 ? x[2*base + 2] : x[base + 1];
    }
    if (t < NF) { s_sum[t] = 0.f; s_sq[t] = 0.f; }
    __syncthreads();

    f32x4 acc[7];
    #pragma unroll
    for (int nf = 0; nf < 7; ++nf) acc[nf] = (f32x4){0.f,0.f,0.f,0.f};

    const int arow = t >> 3, aj = t & 7;
    const float* rrow = er + (size_t)s_ri[arow] * EMB;
    const float* vrow = ev + (size_t)s_vi[arow] * EMB;
    const int acol = ((aj >> 1) ^ ((arow >> 1) & 3)) * 8 + (aj & 1) * 4;

    for (int ks = 0; ks < 7; ++ks) {
        int kb = ks*32 + aj*4;
        float4 v;
        if (kb + 3 < EMB)      v = *(const float4*)&rrow[kb];
        else if (kb < 2*EMB)   v = *(const float4*)&vrow[kb - EMB];
        else                   v = (float4){0.f,0.f,0.f,0.f};
        half4 hi4, lo4;
        hi4[0]=(_Float16)v.x; lo4[0]=(_Float16)(v.x-(float)hi4[0]);
        hi4[1]=(_Float16)v.y; lo4[1]=(_Float16)(v.y-(float)hi4[1]);
        hi4[2]=(_Float16)v.z; lo4[2]=(_Float16)(v.z-(float)hi4[2]);
        hi4[3]=(_Float16)v.w; lo4[3]=(_Float16)(v.w-(float)hi4[3]);
        *(half4*)&s_ah[arow*32 + acol] = hi4;
        *(half4*)&s_al[arow*32 + acol] = lo4;

        // stage Whi/Wlo 224x32 each (pre-swizzled in global; linear copy)
        #pragma unroll
        for (int i = 0; i < 7; ++i) {
            int cid = 4*i + wave;                  // 0..27
            int part = cid >= 14;
            int lc = part ? cid - 14 : cid;
            int c = lc*64 + lane;
            int row = c >> 2, slot = c & 3;
            const _Float16* src = (part ? wlo : whi) + row*KP + ks*32 + slot*8;
            char* dst = (char*)(part ? s_wl : s_wh) + lc*1024;
            gload16(src, dst);
        }
        __syncthreads();

        half8 ah = *(const half8*)&s_ah[(wm*16 + cx)*32 + rdsw];
        half8 al = *(const half8*)&s_al[(wm*16 + cx)*32 + rdsw];
        #pragma unroll
        for (int nf = 0; nf < 7; ++nf) {
            int rb = (wn*112 + nf*16 + cx)*32 + rdsw;
            half8 bh = *(const half8*)&s_wh[rb];
            half8 bl = *(const half8*)&s_wl[rb];
            acc[nf] = __builtin_amdgcn_mfma_f32_16x16x32_f16(ah, bh, acc[nf], 0,0,0);
            acc[nf] = __builtin_amdgcn_mfma_f32_16x16x32_f16(ah, bl, acc[nf], 0,0,0);
            acc[nf] = __builtin_amdgcn_mfma_f32_16x16x32_f16(al, bh, acc[nf], 0,0,0);
        }
        __syncthreads();
    }

    // epilogue: +bias, write m_raw (f16), block stats
    #pragma unroll
    for (int nf = 0; nf < 7; ++nf) {
        int f = wn*112 + nf*16 + cx;
        bool valid = (f < NF);
        float bias = valid ? cb[f] : 0.f;
        float ps = 0.f, pq = 0.f;
        #pragma unroll
        for (int reg = 0; reg < 4; ++reg) {
            float vv = acc[nf][reg] + bias;
            if (valid) {
                int R = R0 + wm*16 + q*4 + reg;
                m_raw[(size_t)R*NF + f] = (_Float16)vv;
                ps += vv; pq += vv*vv;
            }
        }
        ps += __shfl_xor(ps, 16); ps += __shfl_xor(ps, 32);
        pq += __shfl_xor(pq, 16); pq += __shfl_xor(pq, 32);
        if (valid && q == 0) { atomicAdd(&s_sum[f], ps); atomicAdd(&s_sq[f], pq); }
    }
    __syncthreads();
    if (t < NF) {
        float* g = gshad + (blockIdx.x & 15) * 400;
        atomicAdd(&g[t], s_sum[t]);
        atomicAdd(&g[t + 200], s_sq[t]);
    }
}

// ---------------- k2: finalize BN scale/shift (reduce 16 shadows) ----------
__global__ void k2_stats(const float* __restrict__ gshad,
                         const float* __restrict__ gamma,
                         const float* __restrict__ beta,
                         float* __restrict__ scale,
                         float* __restrict__ shift)
{
    int t = threadIdx.x;
    if (t < NF) {
        float s = 0.f, qq = 0.f;
        #pragma unroll
        for (int c = 0; c < 16; ++c) { s += gshad[c*400 + t]; qq += gshad[c*400 + 200 + t]; }
        float inv = 1.0f / (float)NROWS;
        float mu  = s * inv;
        float var = qq * inv - mu*mu;
        float rs  = rsqrtf(var + BN_EPS);
        float sc  = rs * gamma[t];
        scale[t] = sc;
        shift[t] = beta[t] - mu*sc;
    }
}

// ---------------- k_h2: m_raw -> m_h = f16(relu(BN(m))), swizzled, padded --
__launch_bounds__(256)
__global__ void k_h2(const _Float16* __restrict__ m_raw,
                     const float* __restrict__ scale,
                     const float* __restrict__ shift,
                     _Float16* __restrict__ m_h)
{
    int id = blockIdx.x * 256 + threadIdx.x;   // NROWS*28 total
    int R = id / 28, s = id - R*28;
    int tile = s >> 2, ls = s & 3, key = (R >> 1) & 3;
    int col = tile*32 + (ls ^ key)*8;
    half8 o;
    if (s < 25) {
        half8 in = *(const half8*)&m_raw[(size_t)R*NF + s*8];
        #pragma unroll
        for (int j = 0; j < 8; ++j) {
            int k = s*8 + j;
            float v = fmaxf((float)in[j] * scale[k] + shift[k], 0.f);
            o[j] = (_Float16)v;
        }
    } else {
        #pragma unroll
        for (int j = 0; j < 8; ++j) o[j] = (_Float16)0.f;
    }
    *(half8*)&m_h[(size_t)R*KP + col] = o;
}

// ---------------- k_init: out[b] = fb ---------------------------------------
__global__ void k_init(const float* __restrict__ fb, float* __restrict__ out)
{
    int i = blockIdx.x * 256 + threadIdx.x;
    if (i < B_) out[i] = fb[0];
}

// ---------------- k3: f16 MFMA GEMM + min over arity + fused final ---------
// Block 256 (4 waves 2Mx2N), tile 96M x 160N (=80 o-pairs), K=224.
__launch_bounds__(256)
__global__ void k3_mfma(const _Float16* __restrict__ m_h,
                        const _Float16* __restrict__ W_h,
                        const float* __restrict__ gb,
                        const float* __restrict__ fW,
                        float* __restrict__ out)
{
    __shared__ __align__(16) char smem[16384];
    _Float16* s_a = (_Float16*)smem;            // 96 x 32 f16
    _Float16* s_b = (_Float16*)(smem + 6144);   // 160 x 32 f16
    float*    s_ep = (float*)smem;

    const int t    = threadIdx.x;
    const int lane = t & 63;
    const int wave = t >> 6;
    const int wm   = wave >> 1, wn = wave & 1;
    const int R0   = blockIdx.y * 96;
    const int N0   = blockIdx.x * 160;
    const int q    = lane >> 4, cx = lane & 15;
    const int rdsw = (q ^ ((cx >> 1) & 3)) * 8;

    f32x4 acc[3][5];
    #pragma unroll
    for (int mf = 0; mf < 3; ++mf)
        #pragma unroll
        for (int nf = 0; nf < 5; ++nf)
            acc[mf][nf] = (f32x4){0.f,0.f,0.f,0.f};

    for (int ks = 0; ks < 7; ++ks) {
        const int k0 = ks * 32;
        #pragma unroll
        for (int i = 0; i < 4; ++i) {
            int j = wave + 4*i;
            if (j < 6) {
                int c = j*64 + lane;
                int row = c >> 2, slot = c & 3;
                gload16(m_h + (size_t)(R0+row)*KP + k0 + slot*8, (char*)s_a + j*1024);
            } else {
                int c = (j-6)*64 + lane;
                int row = c >> 2, slot = c & 3;
                gload16(W_h + (size_t)(N0+row)*KP + k0 + slot*8, (char*)s_b + (j-6)*1024);
            }
        }
        __syncthreads();

        half8 av[3], bv[5];
        #pragma unroll
        for (int mf = 0; mf < 3; ++mf)
            av[mf] = *(const half8*)&s_a[(wm*48 + mf*16 + cx)*32 + rdsw];
        #pragma unroll
        for (int nf = 0; nf < 5; ++nf)
            bv[nf] = *(const half8*)&s_b[(wn*80 + nf*16 + cx)*32 + rdsw];
        #pragma unroll
        for (int mf = 0; mf < 3; ++mf)
            #pragma unroll
            for (int nf = 0; nf < 5; ++nf)
                acc[mf][nf] = __builtin_amdgcn_mfma_f32_16x16x32_f16(
                                  av[mf], bv[nf], acc[mf][nf], 0, 0, 0);
        __syncthreads();
    }

    // fused epilogue: min over 6 rows -> relu(minA+minC+gb)*fW -> atomicAdd
    float gbv = 0.f, fwv = 0.f;
    if (lane < 40) {
        int o = (N0 >> 1) + wn*40 + lane;
        gbv = gb[o]; fwv = fW[o];
    }
    float* wep = s_ep + wave * 960;
    #pragma unroll
    for (int p = 0; p < 4; ++p) {
        __syncthreads();
        #pragma unroll
        for (int mf = 0; mf < 3; ++mf)
            #pragma unroll
            for (int reg = 0; reg < 4; ++reg) {
                int r = mf*16 + q*4 + reg;
                if (r >= p*12 && r < p*12 + 12) {
                    #pragma unroll
                    for (int nf = 0; nf < 5; ++nf)
                        wep[(r - p*12)*80 + nf*16 + cx] = acc[mf][nf][reg];
                }
            }
        __syncthreads();
        #pragma unroll
        for (int g = 0; g < 2; ++g) {
            float val = 0.f;
            if (lane < 40) {
                float vA = wep[(g*6)*80 + 2*lane];
                float vC = wep[(g*6)*80 + 2*lane + 1];
                #pragma unroll
                for (int r2 = 1; r2 < 6; ++r2) {
                    vA = fminf(vA, wep[(g*6 + r2)*80 + 2*lane]);
                    vC = fminf(vC, wep[(g*6 + r2)*80 + 2*lane + 1]);
                }
                val = fmaxf(vA + vC + gbv, 0.f) * fwv;
            }
            #pragma unroll
            for (int off = 32; off > 0; off >>= 1) val += __shfl_down(val, off);
            if (lane == 0) atomicAdd(&out[R0/6 + wm*8 + p*2 + g], val);
        }
    }
}

extern "C" void kernel_launch(void* const* d_in, const int* in_sizes, int n_in,
                              void* d_out, int out_size, void* d_ws, size_t ws_size,
                              hipStream_t stream)
{
    const int*   x   = (const int*)  d_in[0];
    const float* er  = (const float*)d_in[1];
    const float* ev  = (const float*)d_in[2];
    const float* cw  = (const float*)d_in[3];
    const float* cb  = (const float*)d_in[4];
    const float* gam = (const float*)d_in[5];
    const float* bet = (const float*)d_in[6];
    const float* gW  = (const float*)d_in[7];
    const float* gb  = (const float*)d_in[8];
    const float* fW  = (const float*)d_in[9];
    const float* fb  = (const float*)d_in[10];

    float* ws = (float*)d_ws;
    _Float16* m_raw = (_Float16*)(ws + MRAW_OFF);
    _Float16* m_h   = (_Float16*)(ws + MH_OFF);
    _Float16* W_h   = (_Float16*)(ws + WH_OFF);
    _Float16* whi   = (_Float16*)(ws + WHI_OFF);
    _Float16* wlo   = (_Float16*)(ws + WLO_OFF);
    float* gshad    = ws + STAT_OFF;            // 16*400
    float* scale    = gshad + 6400;
    float* shift    = scale + 200;
    float* out      = (float*)d_out;

    hipMemsetAsync(gshad, 0, 16*400*sizeof(float), stream);

    k0_prep<<<287, 256, 0, stream>>>(cw, gW, whi, wlo, W_h);
    k1_mfma<<<NROWS/32, 256, 0, stream>>>(x, er, ev, whi, wlo, cb, m_raw, gshad);
    k2_stats<<<1, 256, 0, stream>>>(gshad, gam, bet, scale, shift);
    k_h2<<<NROWS*28/256, 256, 0, stream>>>(m_raw, scale, shift, m_h);
    k_init<<<(B_+255)/256, 256, 0, stream>>>(fb, out);
    k3_mfma<<<dim3(15, NROWS/96), 256, 0, stream>>>(m_h, W_h, gb, fW, out);
}

// Round 5
// 121.300 us; speedup vs baseline: 5.8789x; 1.1148x over previous
//
#include <hip/hip_runtime.h>
#include <hip/hip_bf16.h>
#include <hip/hip_fp16.h>

#define B_    4096
#define ARITY 6
#define EMB   100
#define NF    200
#define FC    1200
#define NROWS (B_*ARITY)      // 24576
#define MPAD  (B_*8)          // 32768 padded M rows (8 per batch, 2 sentinel)
#define NPAD  2432            // 38 tiles of 64 (pairs interleaved; >=2400 real)
#define NT3   (NPAD/64)       // 38
#define BN_EPS 1e-5f
#define KP    224
#define SENT  32768.0f

typedef _Float16 half8 __attribute__((ext_vector_type(8)));
typedef float f32x4 __attribute__((ext_vector_type(4)));

// ws float offsets
#define MRAW_OFF 0              // m_raw f16 [24576][200]
#define MH_OFF   2457600        // m_h   f16 [32768][224] (padded, swizzled)
#define WH_OFF   6127616        // W_h   f16 [2432][224]  (interleaved pairs, swizzled)
#define WHI_OFF  6400000        // Whi   f16 [224][224]
#define WLO_OFF  6425088        // Wlo   f16 [224][224]
#define STAT_OFF 6450176        // gshad[16][400] + scale[200] + shift[200]

__device__ __forceinline__ void gload16(const void* g, void* l) {
    __builtin_amdgcn_global_load_lds(
        (const __attribute__((address_space(1))) void*)g,
        (__attribute__((address_space(3))) void*)l, 16, 0, 0);
}

__device__ __forceinline__ float4 ld4(const float* rr, const float* vr, int e) {
    if (e < EMB)        return *(const float4*)&rr[e];
    else if (e < 2*EMB) return *(const float4*)&vr[e - EMB];
    float4 z = {0.f,0.f,0.f,0.f}; return z;
}

// ---------------- k0: weight prep ------------------------------------------
// Swizzle: within each [row][32] f16 K-tile, 16B-slot s -> s ^ ((row>>1)&3).
__launch_bounds__(256)
__global__ void k0_prep(const float* __restrict__ cw, const float* __restrict__ gW,
                        _Float16* __restrict__ whi, _Float16* __restrict__ wlo,
                        _Float16* __restrict__ W_h)
{
    int id = blockIdx.x * 256 + threadIdx.x;
    if (id < 224*28) {
        int f = id / 28, s = id - f*28;
        int tile = s >> 2, ls = s & 3, key = (f >> 1) & 3;
        int col = tile*32 + (ls ^ key)*8;
        half8 h, l;
        #pragma unroll
        for (int j = 0; j < 8; ++j) {
            int k = s*8 + j;
            float v = (f < NF && k < NF) ? cw[f*NF + k] : 0.f;
            _Float16 hi = (_Float16)v;
            h[j] = hi; l[j] = (_Float16)(v - (float)hi);
        }
        *(half8*)&whi[f*KP + col] = h;
        *(half8*)&wlo[f*KP + col] = l;
    } else if (id < 224*28 + NPAD*28) {
        int id2 = id - 224*28;
        int n = id2 / 28, s = id2 - n*28;
        int o = n >> 1, hf = n & 1;
        int tile = s >> 2, ls = s & 3, key = (n >> 1) & 3;
        int col = tile*32 + (ls ^ key)*8;
        half8 h;
        #pragma unroll
        for (int j = 0; j < 8; ++j) {
            int k = s*8 + j;
            float v = 0.f;
            if (k < NF && n < 2*FC) v = gW[(size_t)o*400 + hf*200 + k];
            if (k == NF) v = SENT;           // sentinel column
            h[j] = (_Float16)v;
        }
        *(half8*)&W_h[(size_t)n*KP + col] = h;
    }
}

// ---------------- k1: gather + split-f16 MFMA conv + stats -----------------
// Block 256 (4 waves 2Mx2N), tile 64M x 224N, K=224 in 7 steps of 32.
__launch_bounds__(256)
__global__ void k1_mfma(const int* __restrict__ x,
                        const float* __restrict__ er,
                        const float* __restrict__ ev,
                        const _Float16* __restrict__ whi,
                        const _Float16* __restrict__ wlo,
                        const float* __restrict__ cb,
                        _Float16* __restrict__ m_raw,
                        float* __restrict__ gshad)
{
    __shared__ __align__(16) _Float16 s_ah[64*32], s_al[64*32];
    __shared__ __align__(16) _Float16 s_wh[224*32], s_wl[224*32];
    __shared__ float s_sum[200], s_sq[200];
    __shared__ int s_ri[64], s_vi[64];

    const int t = threadIdx.x, lane = t & 63, wave = t >> 6;
    const int wm = wave >> 1, wn = wave & 1;
    const int R0 = blockIdx.x * 64;
    const int q = lane >> 4, cx = lane & 15;
    const int rdsw = (q ^ ((cx >> 1) & 3)) * 8;

    if (t < 64) {
        int R = R0 + t, b = R / ARITY, a = R - b * ARITY;
        bool is64 = ((x[1] | x[3] | x[5] | x[7]) == 0);
        int base = b * (2*ARITY) + 2*a;
        s_ri[t] = is64 ? x[2*base]     : x[base];
        s_vi[t] = is64 ? x[2*base + 2] : x[base + 1];
    }
    if (t < NF) { s_sum[t] = 0.f; s_sq[t] = 0.f; }
    __syncthreads();

    f32x4 acc[2][7];
    #pragma unroll
    for (int mf = 0; mf < 2; ++mf)
        #pragma unroll
        for (int nf = 0; nf < 7; ++nf) acc[mf][nf] = (f32x4){0.f,0.f,0.f,0.f};

    const int arow = t >> 2, aj = t & 3;
    const float* rrow = er + (size_t)s_ri[arow] * EMB;
    const float* vrow = ev + (size_t)s_vi[arow] * EMB;
    const int acol = (aj ^ ((arow >> 1) & 3)) * 8;

    for (int ks = 0; ks < 7; ++ks) {
        int e0 = ks*32 + aj*8;
        float4 v0 = ld4(rrow, vrow, e0);
        float4 v1 = ld4(rrow, vrow, e0 + 4);
        half8 hi, lo;
        hi[0]=(_Float16)v0.x; lo[0]=(_Float16)(v0.x-(float)hi[0]);
        hi[1]=(_Float16)v0.y; lo[1]=(_Float16)(v0.y-(float)hi[1]);
        hi[2]=(_Float16)v0.z; lo[2]=(_Float16)(v0.z-(float)hi[2]);
        hi[3]=(_Float16)v0.w; lo[3]=(_Float16)(v0.w-(float)hi[3]);
        hi[4]=(_Float16)v1.x; lo[4]=(_Float16)(v1.x-(float)hi[4]);
        hi[5]=(_Float16)v1.y; lo[5]=(_Float16)(v1.y-(float)hi[5]);
        hi[6]=(_Float16)v1.z; lo[6]=(_Float16)(v1.z-(float)hi[6]);
        hi[7]=(_Float16)v1.w; lo[7]=(_Float16)(v1.w-(float)hi[7]);
        *(half8*)&s_ah[arow*32 + acol] = hi;
        *(half8*)&s_al[arow*32 + acol] = lo;

        #pragma unroll
        for (int i = 0; i < 7; ++i) {
            int cid = 4*i + wave;                  // 0..27
            int part = cid >= 14;
            int lc = part ? cid - 14 : cid;
            int c = lc*64 + lane;
            int row = c >> 2, slot = c & 3;
            const _Float16* src = (part ? wlo : whi) + row*KP + ks*32 + slot*8;
            char* dst = (char*)(part ? s_wl : s_wh) + lc*1024;
            gload16(src, dst);
        }
        __syncthreads();

        half8 ah[2], al[2];
        #pragma unroll
        for (int mf = 0; mf < 2; ++mf) {
            ah[mf] = *(const half8*)&s_ah[(wm*32 + mf*16 + cx)*32 + rdsw];
            al[mf] = *(const half8*)&s_al[(wm*32 + mf*16 + cx)*32 + rdsw];
        }
        #pragma unroll
        for (int nf = 0; nf < 7; ++nf) {
            int rb = (wn*112 + nf*16 + cx)*32 + rdsw;
            half8 bh = *(const half8*)&s_wh[rb];
            half8 bl = *(const half8*)&s_wl[rb];
            #pragma unroll
            for (int mf = 0; mf < 2; ++mf) {
                acc[mf][nf] = __builtin_amdgcn_mfma_f32_16x16x32_f16(ah[mf], bh, acc[mf][nf], 0,0,0);
                acc[mf][nf] = __builtin_amdgcn_mfma_f32_16x16x32_f16(ah[mf], bl, acc[mf][nf], 0,0,0);
                acc[mf][nf] = __builtin_amdgcn_mfma_f32_16x16x32_f16(al[mf], bh, acc[mf][nf], 0,0,0);
            }
        }
        __syncthreads();
    }

    // epilogue: +bias, write m_raw (f16), block stats
    #pragma unroll
    for (int mf = 0; mf < 2; ++mf) {
        #pragma unroll
        for (int nf = 0; nf < 7; ++nf) {
            int f = wn*112 + nf*16 + cx;
            bool valid = (f < NF);
            float bias = valid ? cb[f] : 0.f;
            float ps = 0.f, pq = 0.f;
            #pragma unroll
            for (int reg = 0; reg < 4; ++reg) {
                float vv = acc[mf][nf][reg] + bias;
                if (valid) {
                    int R = R0 + wm*32 + mf*16 + q*4 + reg;
                    m_raw[(size_t)R*NF + f] = (_Float16)vv;
                    ps += vv; pq += vv*vv;
                }
            }
            ps += __shfl_xor(ps, 16); ps += __shfl_xor(ps, 32);
            pq += __shfl_xor(pq, 16); pq += __shfl_xor(pq, 32);
            if (valid && q == 0) { atomicAdd(&s_sum[f], ps); atomicAdd(&s_sq[f], pq); }
        }
    }
    __syncthreads();
    if (t < NF) {
        float* g = gshad + (blockIdx.x & 15) * 400;
        atomicAdd(&g[t], s_sum[t]);
        atomicAdd(&g[t + 200], s_sq[t]);
    }
}

// ---------------- k2: finalize BN scale/shift ------------------------------
__global__ void k2_stats(const float* __restrict__ gshad,
                         const float* __restrict__ gamma,
                         const float* __restrict__ beta,
                         float* __restrict__ scale,
                         float* __restrict__ shift)
{
    int t = threadIdx.x;
    if (t < NF) {
        float s = 0.f, qq = 0.f;
        #pragma unroll
        for (int c = 0; c < 16; ++c) { s += gshad[c*400 + t]; qq += gshad[c*400 + 200 + t]; }
        float inv = 1.0f / (float)NROWS;
        float mu  = s * inv;
        float var = qq * inv - mu*mu;
        float rs  = rsqrtf(var + BN_EPS);
        float sc  = rs * gamma[t];
        scale[t] = sc;
        shift[t] = beta[t] - mu*sc;
    }
}

// ---------------- k_h2: m_raw -> padded m_h (8 rows/batch, sentinel) -------
__launch_bounds__(256)
__global__ void k_h2(const _Float16* __restrict__ m_raw,
                     const float* __restrict__ scale,
                     const float* __restrict__ shift,
                     _Float16* __restrict__ m_h)
{
    int id = blockIdx.x * 256 + threadIdx.x;   // MPAD*28 total
    int Rp = id / 28, s = id - Rp*28;
    int b = Rp >> 3, a = Rp & 7;
    int tile = s >> 2, ls = s & 3, key = (Rp >> 1) & 3;
    int col = tile*32 + (ls ^ key)*8;
    half8 o;
    #pragma unroll
    for (int j = 0; j < 8; ++j) o[j] = (_Float16)0.f;
    if (a < ARITY) {
        if (s < 25) {
            half8 in = *(const half8*)&m_raw[(size_t)(b*ARITY + a)*NF + s*8];
            #pragma unroll
            for (int j = 0; j < 8; ++j) {
                int k = s*8 + j;
                o[j] = (_Float16)fmaxf((float)in[j] * scale[k] + shift[k], 0.f);
            }
        }
    } else {
        if (s == 25) o[0] = (_Float16)1.0f;    // k==200 sentinel unit
    }
    *(half8*)&m_h[(size_t)Rp*KP + col] = o;
}

// ---------------- k_init: out[b] = fb --------------------------------------
__global__ void k_init(const float* __restrict__ fb, float* __restrict__ out)
{
    int i = blockIdx.x * 256 + threadIdx.x;
    if (i < B_) out[i] = fb[0];
}

// ---------------- k3: A-resident MFMA GEMM + in-register min + final -------
// Grid 256 (1 block/CU): block owns 128 padded M rows (16 batches), loops 38
// N-tiles of 64. A panel hoisted to regs; B double-buffered via gload_lds.
__launch_bounds__(256)
__global__ void k3_mfma(const _Float16* __restrict__ m_h,
                        const _Float16* __restrict__ W_h,
                        const float* __restrict__ gb,
                        const float* __restrict__ fW,
                        float* __restrict__ out)
{
    __shared__ __align__(16) char smem[57344];

    const int t = threadIdx.x, lane = t & 63, wave = t >> 6;
    const int wm = wave >> 1, wn = wave & 1;
    const int q = lane >> 4, cx = lane & 15;
    const int rdsw = (q ^ ((cx >> 1) & 3)) * 8;
    const int R0 = blockIdx.x * 128;

    // stage whole A panel (128 x 224 f16 = 57344 B) into smem
    {
        const char* src = (const char*)(m_h + (size_t)R0 * KP);
        #pragma unroll
        for (int i = 0; i < 14; ++i) {
            int j = wave + 4*i;                  // 0..55
            gload16(src + (size_t)(j*64 + lane)*16, smem + j*1024);
        }
    }
    __syncthreads();

    // A fragments to registers: rows wm*64 + mf*16 + cx
    f32x4 av[4][7];
    {
        const _Float16* sa = (const _Float16*)smem;
        #pragma unroll
        for (int mf = 0; mf < 4; ++mf) {
            int row = wm*64 + mf*16 + cx;
            #pragma unroll
            for (int ks = 0; ks < 7; ++ks) {
                av[mf][ks] = *(const f32x4*)&sa[row*KP + ks*32 + rdsw];
                asm volatile("" : "+v"(av[mf][ks]));   // pin: smem gets reused
            }
        }
    }
    __syncthreads();                             // all A reads complete

    // prologue: stage B tile 0 into half 0
    {
        const char* src = (const char*)W_h;
        #pragma unroll
        for (int i = 0; i < 7; ++i) {
            int j = wave + 4*i;
            gload16(src + (size_t)(j*64 + lane)*16, smem + j*1024);
        }
    }
    __syncthreads();

    float preg[4] = {0.f, 0.f, 0.f, 0.f};

    for (int nt = 0; nt < NT3; ++nt) {
        const _Float16* cur = (const _Float16*)(smem + (nt & 1) * 28672);
        char*           nxt = smem + (((nt & 1) ^ 1) * 28672);
        if (nt + 1 < NT3) {
            const char* src = (const char*)W_h + (size_t)(nt + 1) * 28672;
            #pragma unroll
            for (int i = 0; i < 7; ++i) {
                int j = wave + 4*i;
                gload16(src + (size_t)(j*64 + lane)*16, nxt + j*1024);
            }
        }

        f32x4 acc[4][2];
        #pragma unroll
        for (int mf = 0; mf < 4; ++mf)
            #pragma unroll
            for (int nf = 0; nf < 2; ++nf) acc[mf][nf] = (f32x4){0.f,0.f,0.f,0.f};

        #pragma unroll
        for (int ks = 0; ks < 7; ++ks) {
            f32x4 bv[2];
            #pragma unroll
            for (int nf = 0; nf < 2; ++nf)
                bv[nf] = *(const f32x4*)&cur[(wn*32 + nf*16 + cx)*KP + ks*32 + rdsw];
            #pragma unroll
            for (int mf = 0; mf < 4; ++mf)
                #pragma unroll
                for (int nf = 0; nf < 2; ++nf)
                    acc[mf][nf] = __builtin_amdgcn_mfma_f32_16x16x32_f16(
                        __builtin_bit_cast(half8, av[mf][ks]),
                        __builtin_bit_cast(half8, bv[nf]), acc[mf][nf], 0, 0, 0);
        }

        // per-tile register epilogue: min over 8 rows, pair A/C, dot with fW
        #pragma unroll
        for (int mf = 0; mf < 4; ++mf) {
            #pragma unroll
            for (int nf = 0; nf < 2; ++nf) {
                f32x4 a4 = acc[mf][nf];
                float v = fminf(fminf(a4[0], a4[1]), fminf(a4[2], a4[3]));
                v = fminf(v, __shfl_xor(v, 16));        // min over q-pair (8 rows)
                float vp = v + __shfl_xor(v, 1);        // A + C halves
                if (((q & 1) == 0) && ((cx & 1) == 0)) {
                    int o = (nt*64 + wn*32 + nf*16 + cx) >> 1;
                    float gbv = 0.f, fwv = 0.f;
                    if (o < FC) { gbv = gb[o]; fwv = fW[o]; }
                    preg[mf] += fmaxf(vp + gbv, 0.f) * fwv;
                }
            }
        }
        __syncthreads();   // drains vmcnt: next tile staged; cur free for reuse
    }

    #pragma unroll
    for (int mf = 0; mf < 4; ++mf) {
        float v = preg[mf];
        v += __shfl_xor(v, 2);
        v += __shfl_xor(v, 4);
        v += __shfl_xor(v, 8);
        if (cx == 0 && (q & 1) == 0) {
            int bb = blockIdx.x*16 + wm*8 + mf*2 + (q >> 1);
            atomicAdd(&out[bb], v);
        }
    }
}

extern "C" void kernel_launch(void* const* d_in, const int* in_sizes, int n_in,
                              void* d_out, int out_size, void* d_ws, size_t ws_size,
                              hipStream_t stream)
{
    const int*   x   = (const int*)  d_in[0];
    const float* er  = (const float*)d_in[1];
    const float* ev  = (const float*)d_in[2];
    const float* cw  = (const float*)d_in[3];
    const float* cb  = (const float*)d_in[4];
    const float* gam = (const float*)d_in[5];
    const float* bet = (const float*)d_in[6];
    const float* gW  = (const float*)d_in[7];
    const float* gb  = (const float*)d_in[8];
    const float* fW  = (const float*)d_in[9];
    const float* fb  = (const float*)d_in[10];

    float* ws = (float*)d_ws;
    _Float16* m_raw = (_Float16*)(ws + MRAW_OFF);
    _Float16* m_h   = (_Float16*)(ws + MH_OFF);
    _Float16* W_h   = (_Float16*)(ws + WH_OFF);
    _Float16* whi   = (_Float16*)(ws + WHI_OFF);
    _Float16* wlo   = (_Float16*)(ws + WLO_OFF);
    float* gshad    = ws + STAT_OFF;
    float* scale    = gshad + 6400;
    float* shift    = scale + 200;
    float* out      = (float*)d_out;

    (void)hipMemsetAsync(gshad, 0, 16*400*sizeof(float), stream);

    k0_prep<<<(224*28 + NPAD*28 + 255)/256, 256, 0, stream>>>(cw, gW, whi, wlo, W_h);
    k1_mfma<<<NROWS/64, 256, 0, stream>>>(x, er, ev, whi, wlo, cb, m_raw, gshad);
    k2_stats<<<1, 256, 0, stream>>>(gshad, gam, bet, scale, shift);
    k_h2<<<MPAD*28/256, 256, 0, stream>>>(m_raw, scale, shift, m_h);
    k_init<<<(B_+255)/256, 256, 0, stream>>>(fb, out);
    k3_mfma<<<MPAD/128, 256, 0, stream>>>(m_h, W_h, gb, fW, out);
}

// Round 6
// 96.160 us; speedup vs baseline: 7.4160x; 1.2614x over previous
//
#include <hip/hip_runtime.h>
#include <hip/hip_bf16.h>
#include <hip/hip_fp16.h>

#define B_    4096
#define ARITY 6
#define EMB   100
#define NF    200
#define FC    1200
#define NROWS (B_*ARITY)      // 24576
#define MPAD  (B_*8)          // 32768 padded M rows (8 per batch, 2 sentinel)
#define NPAD  2432            // 38 tiles of 64 (A/C pairs interleaved)
#define NT3   (NPAD/64)       // 38
#define BN_EPS 1e-5f
#define KP    224
#define SENT  32768.0f

typedef _Float16 half8 __attribute__((ext_vector_type(8)));
typedef _Float16 half4 __attribute__((ext_vector_type(4)));
typedef float f32x4 __attribute__((ext_vector_type(4)));

// ws float offsets
#define MRAW_OFF 0              // m_raw f16 [24576][200] -> 2,457,600 f
#define WH_OFF   2457600        // W_h f16 [2432][224]    ->   272,384 f
#define WHI_OFF  2729984        // Whi f16 [224][224]     ->    25,088 f
#define WLO_OFF  2755072        // Wlo f16 [224][224]     ->    25,088 f
#define STAT_OFF 2780160        // gshad[16][400] + scale[200] + shift[200]

__device__ __forceinline__ void gload16(const void* g, void* l) {
    __builtin_amdgcn_global_load_lds(
        (const __attribute__((address_space(1))) void*)g,
        (__attribute__((address_space(3))) void*)l, 16, 0, 0);
}

__device__ __forceinline__ float4 ld4(const float* rr, const float* vr, int e) {
    if (e < EMB)        return *(const float4*)&rr[e];
    else if (e < 2*EMB) return *(const float4*)&vr[e - EMB];
    float4 z = {0.f,0.f,0.f,0.f}; return z;
}

// ---------------- k0: weight prep + out init -------------------------------
// Swizzle: within each [row][32] f16 K-tile, 16B-slot s -> s ^ ((row>>1)&3).
#define K0_W1 (224*28)
#define K0_W2 (K0_W1 + NPAD*28)
#define K0_TOT (K0_W2 + B_)
__launch_bounds__(256)
__global__ void k0_prep(const float* __restrict__ cw, const float* __restrict__ gW,
                        const float* __restrict__ fb,
                        _Float16* __restrict__ whi, _Float16* __restrict__ wlo,
                        _Float16* __restrict__ W_h, float* __restrict__ out)
{
    int id = blockIdx.x * 256 + threadIdx.x;
    if (id < K0_W1) {
        int f = id / 28, s = id - f*28;
        int tile = s >> 2, ls = s & 3, key = (f >> 1) & 3;
        int col = tile*32 + (ls ^ key)*8;
        half8 h, l;
        #pragma unroll
        for (int j = 0; j < 8; ++j) {
            int k = s*8 + j;
            float v = (f < NF && k < NF) ? cw[f*NF + k] : 0.f;
            _Float16 hi = (_Float16)v;
            h[j] = hi; l[j] = (_Float16)(v - (float)hi);
        }
        *(half8*)&whi[f*KP + col] = h;
        *(half8*)&wlo[f*KP + col] = l;
    } else if (id < K0_W2) {
        int id2 = id - K0_W1;
        int n = id2 / 28, s = id2 - n*28;
        int o = n >> 1, hf = n & 1;
        int tile = s >> 2, ls = s & 3, key = (n >> 1) & 3;
        int col = tile*32 + (ls ^ key)*8;
        half8 h;
        #pragma unroll
        for (int j = 0; j < 8; ++j) {
            int k = s*8 + j;
            float v = 0.f;
            if (k < NF && n < 2*FC) v = gW[(size_t)o*400 + hf*200 + k];
            if (k == NF) v = SENT;           // sentinel column
            h[j] = (_Float16)v;
        }
        *(half8*)&W_h[(size_t)n*KP + col] = h;
    } else if (id < K0_TOT) {
        out[id - K0_W2] = fb[0];
    }
}

// ---------------- k1: gather + split-f16 MFMA conv + stats -----------------
__launch_bounds__(256)
__global__ void k1_mfma(const int* __restrict__ x,
                        const float* __restrict__ er,
                        const float* __restrict__ ev,
                        const _Float16* __restrict__ whi,
                        const _Float16* __restrict__ wlo,
                        const float* __restrict__ cb,
                        _Float16* __restrict__ m_raw,
                        float* __restrict__ gshad)
{
    __shared__ __align__(16) _Float16 s_ah[64*32], s_al[64*32];
    __shared__ __align__(16) _Float16 s_wh[224*32], s_wl[224*32];
    __shared__ float s_sum[200], s_sq[200];
    __shared__ int s_ri[64], s_vi[64];

    const int t = threadIdx.x, lane = t & 63, wave = t >> 6;
    const int wm = wave >> 1, wn = wave & 1;
    const int R0 = blockIdx.x * 64;
    const int q = lane >> 4, cx = lane & 15;
    const int rdsw = (q ^ ((cx >> 1) & 3)) * 8;

    if (t < 64) {
        int R = R0 + t, b = R / ARITY, a = R - b * ARITY;
        bool is64 = ((x[1] | x[3] | x[5] | x[7]) == 0);
        int base = b * (2*ARITY) + 2*a;
        s_ri[t] = is64 ? x[2*base]     : x[base];
        s_vi[t] = is64 ? x[2*base + 2] : x[base + 1];
    }
    if (t < NF) { s_sum[t] = 0.f; s_sq[t] = 0.f; }
    __syncthreads();

    f32x4 acc[2][7];
    #pragma unroll
    for (int mf = 0; mf < 2; ++mf)
        #pragma unroll
        for (int nf = 0; nf < 7; ++nf) acc[mf][nf] = (f32x4){0.f,0.f,0.f,0.f};

    const int arow = t >> 2, aj = t & 3;
    const float* rrow = er + (size_t)s_ri[arow] * EMB;
    const float* vrow = ev + (size_t)s_vi[arow] * EMB;
    const int acol = (aj ^ ((arow >> 1) & 3)) * 8;

    for (int ks = 0; ks < 7; ++ks) {
        int e0 = ks*32 + aj*8;
        float4 v0 = ld4(rrow, vrow, e0);
        float4 v1 = ld4(rrow, vrow, e0 + 4);
        half8 hi, lo;
        hi[0]=(_Float16)v0.x; lo[0]=(_Float16)(v0.x-(float)hi[0]);
        hi[1]=(_Float16)v0.y; lo[1]=(_Float16)(v0.y-(float)hi[1]);
        hi[2]=(_Float16)v0.z; lo[2]=(_Float16)(v0.z-(float)hi[2]);
        hi[3]=(_Float16)v0.w; lo[3]=(_Float16)(v0.w-(float)hi[3]);
        hi[4]=(_Float16)v1.x; lo[4]=(_Float16)(v1.x-(float)hi[4]);
        hi[5]=(_Float16)v1.y; lo[5]=(_Float16)(v1.y-(float)hi[5]);
        hi[6]=(_Float16)v1.z; lo[6]=(_Float16)(v1.z-(float)hi[6]);
        hi[7]=(_Float16)v1.w; lo[7]=(_Float16)(v1.w-(float)hi[7]);
        *(half8*)&s_ah[arow*32 + acol] = hi;
        *(half8*)&s_al[arow*32 + acol] = lo;

        #pragma unroll
        for (int i = 0; i < 7; ++i) {
            int cid = 4*i + wave;                  // 0..27
            int part = cid >= 14;
            int lc = part ? cid - 14 : cid;
            int c = lc*64 + lane;
            int row = c >> 2, slot = c & 3;
            const _Float16* src = (part ? wlo : whi) + row*KP + ks*32 + slot*8;
            char* dst = (char*)(part ? s_wl : s_wh) + lc*1024;
            gload16(src, dst);
        }
        __syncthreads();

        half8 ah[2], al[2];
        #pragma unroll
        for (int mf = 0; mf < 2; ++mf) {
            ah[mf] = *(const half8*)&s_ah[(wm*32 + mf*16 + cx)*32 + rdsw];
            al[mf] = *(const half8*)&s_al[(wm*32 + mf*16 + cx)*32 + rdsw];
        }
        #pragma unroll
        for (int nf = 0; nf < 7; ++nf) {
            int rb = (wn*112 + nf*16 + cx)*32 + rdsw;
            half8 bh = *(const half8*)&s_wh[rb];
            half8 bl = *(const half8*)&s_wl[rb];
            #pragma unroll
            for (int mf = 0; mf < 2; ++mf) {
                acc[mf][nf] = __builtin_amdgcn_mfma_f32_16x16x32_f16(ah[mf], bh, acc[mf][nf], 0,0,0);
                acc[mf][nf] = __builtin_amdgcn_mfma_f32_16x16x32_f16(ah[mf], bl, acc[mf][nf], 0,0,0);
                acc[mf][nf] = __builtin_amdgcn_mfma_f32_16x16x32_f16(al[mf], bh, acc[mf][nf], 0,0,0);
            }
        }
        __syncthreads();
    }

    #pragma unroll
    for (int mf = 0; mf < 2; ++mf) {
        #pragma unroll
        for (int nf = 0; nf < 7; ++nf) {
            int f = wn*112 + nf*16 + cx;
            bool valid = (f < NF);
            float bias = valid ? cb[f] : 0.f;
            float ps = 0.f, pq = 0.f;
            #pragma unroll
            for (int reg = 0; reg < 4; ++reg) {
                float vv = acc[mf][nf][reg] + bias;
                if (valid) {
                    int R = R0 + wm*32 + mf*16 + q*4 + reg;
                    m_raw[(size_t)R*NF + f] = (_Float16)vv;
                    ps += vv; pq += vv*vv;
                }
            }
            ps += __shfl_xor(ps, 16); ps += __shfl_xor(ps, 32);
            pq += __shfl_xor(pq, 16); pq += __shfl_xor(pq, 32);
            if (valid && q == 0) { atomicAdd(&s_sum[f], ps); atomicAdd(&s_sq[f], pq); }
        }
    }
    __syncthreads();
    if (t < NF) {
        float* g = gshad + (blockIdx.x & 15) * 400;
        atomicAdd(&g[t], s_sum[t]);
        atomicAdd(&g[t + 200], s_sq[t]);
    }
}

// ---------------- k2: finalize BN scale/shift ------------------------------
__global__ void k2_stats(const float* __restrict__ gshad,
                         const float* __restrict__ gamma,
                         const float* __restrict__ beta,
                         float* __restrict__ scale,
                         float* __restrict__ shift)
{
    int t = threadIdx.x;
    if (t < NF) {
        float s = 0.f, qq = 0.f;
        #pragma unroll
        for (int c = 0; c < 16; ++c) { s += gshad[c*400 + t]; qq += gshad[c*400 + 200 + t]; }
        float inv = 1.0f / (float)NROWS;
        float mu  = s * inv;
        float var = qq * inv - mu*mu;
        float rs  = rsqrtf(var + BN_EPS);
        float sc  = rs * gamma[t];
        scale[t] = sc;
        shift[t] = beta[t] - mu*sc;
    }
}

// ---------------- k3: fused BN + A-resident MFMA + min + final -------------
// Grid 256 (1 block/CU), 4 waves. Prologue: build padded/swizzled A panel in
// LDS from m_raw (BN+relu in-reg), hoist A frags to 112 VGPRs. Main loop:
// 38 N-tiles of 64, 4-deep LDS ring staged via global_load_lds, counted
// vmcnt (never 0 mid-loop), raw s_barrier, in-register min/relu-dot epilogue
// with gb/fW from an LDS float2 table.
// LDS: bufs 4x28672 @0 | gbfw2 (1216 float2) @114688 | scsh (448 f) @124416
__launch_bounds__(256)
__global__ void k3_mfma(const _Float16* __restrict__ m_raw,
                        const float* __restrict__ scale,
                        const float* __restrict__ shift,
                        const _Float16* __restrict__ W_h,
                        const float* __restrict__ gb,
                        const float* __restrict__ fW,
                        float* __restrict__ out)
{
    __shared__ __align__(16) char smem[126208];
    float2* gbfw2 = (float2*)(smem + 114688);
    float*  scsh  = (float*)(smem + 124416);

    const int t = threadIdx.x, lane = t & 63, wave = t >> 6;
    const int wm = wave >> 1, wn = wave & 1;
    const int q = lane >> 4, cx = lane & 15;
    const int rdsw = (q ^ ((cx >> 1) & 3)) * 8;

    // ---- prologue: constant tables ----
    for (int i = t; i < 224; i += 256) {
        scsh[i]       = (i < NF) ? scale[i] : 0.f;
        scsh[224 + i] = (i < NF) ? shift[i] : 0.f;
    }
    for (int i = t; i < 1216; i += 256) {
        float g = (i < FC) ? gb[i] : 0.f;
        float f = (i < FC) ? fW[i] : 0.f;
        gbfw2[i] = make_float2(g, f);
    }
    __syncthreads();

    // ---- build padded+swizzled A panel (128 rows x 224 f16) from m_raw ----
    {
        _Float16* sa = (_Float16*)smem;
        for (int c = t; c < 3584; c += 256) {          // 128 rows x 28 chunks
            int Rp = c / 28, s = c - Rp*28;
            int a = Rp & 7, b = Rp >> 3;
            int key = (Rp >> 1) & 3;
            int col = (s >> 2)*32 + ((s & 3) ^ key)*8;
            half8 o;
            #pragma unroll
            for (int j = 0; j < 8; ++j) o[j] = (_Float16)0.f;
            if (a < ARITY && s < 25) {
                int R = (blockIdx.x*16 + b)*ARITY + a;
                half8 in = *(const half8*)&m_raw[(size_t)R*NF + s*8];
                #pragma unroll
                for (int j = 0; j < 8; ++j) {
                    int k = s*8 + j;
                    o[j] = (_Float16)fmaxf((float)in[j]*scsh[k] + scsh[224+k], 0.f);
                }
            } else if (a >= ARITY && s == 25) {
                o[0] = (_Float16)1.0f;                 // k==200 sentinel unit
            }
            *(half8*)&sa[Rp*KP + col] = o;
        }
    }
    __syncthreads();

    // ---- hoist A fragments to registers ----
    f32x4 av[4][7];
    {
        const _Float16* sa = (const _Float16*)smem;
        #pragma unroll
        for (int mf = 0; mf < 4; ++mf) {
            int row = wm*64 + mf*16 + cx;
            #pragma unroll
            for (int ks = 0; ks < 7; ++ks) {
                av[mf][ks] = *(const f32x4*)&sa[row*KP + ks*32 + rdsw];
                asm volatile("" : "+v"(av[mf][ks]));   // pin: smem gets reused
            }
        }
    }
    __syncthreads();   // all A reads complete; drains vmcnt -> count exact

    // ---- stage B tiles 0,1 into ring bufs 0,1 (7 chunks of 1KB per wave) --
    #define STAGE_B(NT_, BUF_) do {                                          \
        const char* _src = (const char*)W_h + (size_t)(NT_) * 28672;         \
        char* _dst = smem + (BUF_) * 28672;                                  \
        _Pragma("unroll")                                                    \
        for (int _i = 0; _i < 7; ++_i) {                                     \
            int _j = wave + 4*_i;                                            \
            gload16(_src + (size_t)(_j*64 + lane)*16, _dst + _j*1024);       \
        }                                                                    \
    } while (0)

    STAGE_B(0, 0);
    STAGE_B(1, 1);

    float preg[4] = {0.f, 0.f, 0.f, 0.f};

    for (int nt = 0; nt < NT3; ++nt) {
        // prefetch nt+2; wait for tile nt only (counted vmcnt, never 0 here)
        if (nt + 2 < NT3) {
            STAGE_B(nt + 2, (nt + 2) & 3);
            asm volatile("s_waitcnt vmcnt(14)" ::: "memory");
        } else if (nt + 2 == NT3) {
            asm volatile("s_waitcnt vmcnt(7)" ::: "memory");
        } else {
            asm volatile("s_waitcnt vmcnt(0)" ::: "memory");
        }
        __builtin_amdgcn_s_barrier();
        __builtin_amdgcn_sched_barrier(0);

        const _Float16* cur = (const _Float16*)(smem + (nt & 3) * 28672);

        f32x4 acc[4][2];
        #pragma unroll
        for (int mf = 0; mf < 4; ++mf)
            #pragma unroll
            for (int nf = 0; nf < 2; ++nf) acc[mf][nf] = (f32x4){0.f,0.f,0.f,0.f};

        #pragma unroll
        for (int ks = 0; ks < 7; ++ks) {
            f32x4 bv[2];
            #pragma unroll
            for (int nf = 0; nf < 2; ++nf)
                bv[nf] = *(const f32x4*)&cur[(wn*32 + nf*16 + cx)*KP + ks*32 + rdsw];
            #pragma unroll
            for (int mf = 0; mf < 4; ++mf)
                #pragma unroll
                for (int nf = 0; nf < 2; ++nf)
                    acc[mf][nf] = __builtin_amdgcn_mfma_f32_16x16x32_f16(
                        __builtin_bit_cast(half8, av[mf][ks]),
                        __builtin_bit_cast(half8, bv[nf]), acc[mf][nf], 0, 0, 0);
        }

        // register epilogue: min over 8 rows, A+C pair, relu, dot with fW
        #pragma unroll
        for (int mf = 0; mf < 4; ++mf) {
            #pragma unroll
            for (int nf = 0; nf < 2; ++nf) {
                f32x4 a4 = acc[mf][nf];
                float v = fminf(fminf(a4[0], a4[1]), fminf(a4[2], a4[3]));
                v = fminf(v, __shfl_xor(v, 16));        // min over q-pair (8 rows)
                float vp = v + __shfl_xor(v, 1);        // A + C halves
                int o = (nt*64 + wn*32 + nf*16 + cx) >> 1;
                float2 gf = gbfw2[o];                   // LDS, not vmem
                float val = fmaxf(vp + gf.x, 0.f) * gf.y;
                if (((q & 1) == 0) && ((cx & 1) == 0)) preg[mf] += val;
            }
        }
        // no trailing barrier: buf[nt&3] is restaged only at iter nt+2,
        // which is after barrier(nt+1) -> all waves done computing tile nt.
    }

    #pragma unroll
    for (int mf = 0; mf < 4; ++mf) {
        float v = preg[mf];
        v += __shfl_xor(v, 2);
        v += __shfl_xor(v, 4);
        v += __shfl_xor(v, 8);
        if (cx == 0 && (q & 1) == 0) {
            int bb = blockIdx.x*16 + wm*8 + mf*2 + (q >> 1);
            atomicAdd(&out[bb], v);
        }
    }
}

extern "C" void kernel_launch(void* const* d_in, const int* in_sizes, int n_in,
                              void* d_out, int out_size, void* d_ws, size_t ws_size,
                              hipStream_t stream)
{
    const int*   x   = (const int*)  d_in[0];
    const float* er  = (const float*)d_in[1];
    const float* ev  = (const float*)d_in[2];
    const float* cw  = (const float*)d_in[3];
    const float* cb  = (const float*)d_in[4];
    const float* gam = (const float*)d_in[5];
    const float* bet = (const float*)d_in[6];
    const float* gW  = (const float*)d_in[7];
    const float* gb  = (const float*)d_in[8];
    const float* fW  = (const float*)d_in[9];
    const float* fb  = (const float*)d_in[10];

    float* ws = (float*)d_ws;
    _Float16* m_raw = (_Float16*)(ws + MRAW_OFF);
    _Float16* W_h   = (_Float16*)(ws + WH_OFF);
    _Float16* whi   = (_Float16*)(ws + WHI_OFF);
    _Float16* wlo   = (_Float16*)(ws + WLO_OFF);
    float* gshad    = ws + STAT_OFF;
    float* scale    = gshad + 6400;
    float* shift    = scale + 200;
    float* out      = (float*)d_out;

    (void)hipMemsetAsync(gshad, 0, 16*400*sizeof(float), stream);

    k0_prep<<<(K0_TOT + 255)/256, 256, 0, stream>>>(cw, gW, fb, whi, wlo, W_h, out);
    k1_mfma<<<NROWS/64, 256, 0, stream>>>(x, er, ev, whi, wlo, cb, m_raw, gshad);
    k2_stats<<<1, 256, 0, stream>>>(gshad, gam, bet, scale, shift);
    k3_mfma<<<MPAD/128, 256, 0, stream>>>(m_raw, scale, shift, W_h, gb, fW, out);
}